// Round 1
// baseline (96.484 us; speedup 1.0000x reference)
//
#include <hip/hip_runtime.h>
#include <cstdint>

// HMQSoftmax: exp2(floor(x/ln2)) -> row sum -> quake rsqrt (bf16 magic + 1 Newton)
// -> v = exp*rs*rs -> block-FP quant (block=16, 8-bit signed mantissa, shared exp).
// Rows of 2048 f32. Bit-exact replication of the numpy/JAX f32 op sequence.

#define LN2F 0.69314718055994530942f
#define COLS 2048

__global__ __launch_bounds__(256) void hmq_softmax_kernel(
    const float* __restrict__ x, float* __restrict__ out) {
    const int tid = threadIdx.x;
    const int rowLocal = tid >> 7;       // 2 rows per block
    const int lane128 = tid & 127;       // 128 threads per row
    const long long row = (long long)blockIdx.x * 2 + rowLocal;
    const float* xr = x + row * COLS;
    float* outr = out + row * COLS;

    // ---- load 16 elements (4 x float4, stride 128 float4s) : fully coalesced ----
    float4 xin[4];
#pragma unroll
    for (int k = 0; k < 4; ++k)
        xin[k] = reinterpret_cast<const float4*>(xr)[lane128 + 128 * k];

    // ---- exp2(floor(x / ln2)) (exact powers of two) + partial sum ----
    float e[16];
    float psum = 0.0f;
#pragma unroll
    for (int k = 0; k < 4; ++k) {
        float xs[4] = {xin[k].x, xin[k].y, xin[k].z, xin[k].w};
#pragma unroll
        for (int j = 0; j < 4; ++j) {
            // IEEE f32 division (must match reference rounding exactly)
            float qf = floorf(xs[j] / LN2F);
            float ev = ldexpf(1.0f, (int)qf);   // exact 2^q
            e[k * 4 + j] = ev;
            psum += ev;                          // exact: powers of 2, sum < 2^(qmin+24)
        }
    }

    // ---- row sum: wave shuffle reduce (order-independent: all adds exact) ----
    float wsum = psum;
#pragma unroll
    for (int off = 1; off < 64; off <<= 1)
        wsum += __shfl_xor(wsum, off, 64);

    __shared__ float lds[4];
    const int wave = tid >> 6;
    if ((tid & 63) == 0) lds[wave] = wsum;
    __syncthreads();
    const float s = lds[rowLocal * 2] + lds[rowLocal * 2 + 1];

    // ---- quake rsqrt: bf16 RNE cast, int16 magic, 1 Newton step (bit-exact) ----
    uint32_t ub = __float_as_uint(s);
    uint32_t lsb = (ub >> 16) & 1u;
    uint16_t bbits = (uint16_t)((ub + 0x7FFFu + lsb) >> 16);  // f32->bf16 RNE (s>0, finite)
    int16_t ii = (int16_t)bbits;
    ii = (int16_t)(24375 - (ii >> 1));
    float y = __uint_as_float(((uint32_t)(uint16_t)ii) << 16);
    float xh = __fmul_rn(s, 0.5f);
    float t = __fmul_rn(__fmul_rn(xh, y), y);
    float r = __fsub_rn(1.5f, t);        // separate ops: no FMA contraction
    float rs = __fmul_rn(y, r);

    // ---- v = (e*rs)*rs ; BFP quant per 16-block (4 lanes per block) ----
#pragma unroll
    for (int k = 0; k < 4; ++k) {
        float v[4];
        float m = 0.0f;
#pragma unroll
        for (int j = 0; j < 4; ++j) {
            v[j] = __fmul_rn(__fmul_rn(e[k * 4 + j], rs), rs);  // all > 0
            m = fmaxf(m, v[j]);
        }
        // maxabs across the 4-lane group owning this 16-block
        m = fmaxf(m, __shfl_xor(m, 1, 64));
        m = fmaxf(m, __shfl_xor(m, 2, 64));
        // shared_exp = floor(log2(m)) + 1 = frexp exponent (m = f*2^ex, f in [0.5,1))
        int ex;
        (void)frexpf(m, &ex);            // m==0 -> ex=0 -> matches ref's zero-block path
        float scale = ldexpf(1.0f, ex - 7);
        float inv_scale = ldexpf(1.0f, 7 - ex);
        float4 o;
        float* op = &o.x;
#pragma unroll
        for (int j = 0; j < 4; ++j) {
            float qv = rintf(__fmul_rn(v[j], inv_scale));  // exact scale; half-to-even
            qv = fminf(fmaxf(qv, -128.0f), 127.0f);
            op[j] = __fmul_rn(qv, scale);
        }
        reinterpret_cast<float4*>(outr)[lane128 + 128 * k] = o;
    }
}

extern "C" void kernel_launch(void* const* d_in, const int* in_sizes, int n_in,
                              void* d_out, int out_size, void* d_ws, size_t ws_size,
                              hipStream_t stream) {
    const float* x = (const float*)d_in[0];
    float* out = (float*)d_out;
    const long long total = in_sizes[0];
    const int nrows = (int)(total / COLS);        // 32768
    const int grid = nrows / 2;                   // 2 rows per 256-thread block
    hmq_softmax_kernel<<<grid, 256, 0, stream>>>(x, out);
}